// Round 1
// baseline (17.552 us; speedup 1.0000x reference)
//
#include <hip/hip_runtime.h>

// Paste2dMulti: N=64, M=8, C=3, H=W=64, canvas l=256.
// out[n,0,r,col] = min(1, sum_{m,c} mask(n,m,r,col) * paste(n,m,c,r,col))
// paste(n,m,c,r,col) = images[n,m,c, r - y0, col - x0] if in [0,64)^2 else 0,
//   where x0 = trunc(coords[n,m,0]), y0 = trunc(coords[n,m,1]).
// mask = clamp(r - c1 + 1, 0,1)*clamp(c3 + 1 - r, 0,1)
//      * clamp(col - c0 + 1,0,1)*clamp(c2 + 1 - col,0,1).

__device__ __forceinline__ float clamp01(float v) {
    return fminf(fmaxf(v, 0.0f), 1.0f);   // -> v_med3_f32
}

__global__ __launch_bounds__(256) void Paste2dMulti_kernel(
    const float* __restrict__ coords,   // [64][8][4]
    const float* __restrict__ images,   // [64][8][3][64][64]
    float* __restrict__ out)            // [64][1][256][256]
{
    const int bid = blockIdx.x;     // 64*256 blocks: one per (n, row)
    const int n   = bid >> 8;       // block-uniform
    const int r   = bid & 255;      // block-uniform
    const int col = threadIdx.x;    // 0..255

    const float fr = (float)r;
    const float fc = (float)col;

    const float* cbase = coords + n * (8 * 4);
    const float* ibase = images + (size_t)n * (8 * 3 * 4096);

    float acc = 0.0f;

    #pragma unroll
    for (int m = 0; m < 8; ++m) {
        const float c0 = cbase[m * 4 + 0];
        const float c1 = cbase[m * 4 + 1];
        const float c2 = cbase[m * 4 + 2];
        const float c3 = cbase[m * 4 + 3];

        const int y0 = (int)c1;     // trunc (coords >= 0)
        const int sr = r - y0;
        if (sr < 0 || sr >= 64) continue;   // wave-uniform branch

        const int x0 = (int)c0;
        const int sc = col - x0;
        if (sc < 0 || sc >= 64) continue;

        const float ym = clamp01(fr - c1 + 1.0f) * clamp01(c3 + 1.0f - fr);
        const float xm = clamp01(fc - c0 + 1.0f) * clamp01(c2 + 1.0f - fc);

        const float* p = ibase + m * (3 * 4096) + sr * 64 + sc;
        const float s = p[0] + p[4096] + p[2 * 4096];   // sum over C
        acc = fmaf(xm * ym, s, acc);
    }

    out[n * 65536 + r * 256 + col] = fminf(1.0f, acc);
}

extern "C" void kernel_launch(void* const* d_in, const int* in_sizes, int n_in,
                              void* d_out, int out_size, void* d_ws, size_t ws_size,
                              hipStream_t stream) {
    const float* coords = (const float*)d_in[0];
    const float* images = (const float*)d_in[1];
    float* out = (float*)d_out;

    // 64 batches * 256 rows, 256 threads = one output column each.
    Paste2dMulti_kernel<<<64 * 256, 256, 0, stream>>>(coords, images, out);
}